// Round 1
// baseline (153.486 us; speedup 1.0000x reference)
//
#include <hip/hip_runtime.h>
#include <hip/hip_bf16.h>

// Problem constants
constexpr int   kN    = 4096;
constexpr int   kD    = 256;
constexpr float kNU   = 3.0f;
// SIGMA = 1.0, BETA = 0.5 folded into formulas below.

using bf16x8 = __attribute__((ext_vector_type(8))) __bf16;
using f32x4  = __attribute__((ext_vector_type(4))) float;

// ---------------------------------------------------------------------------
// K1: per-row norms, student-t coefficient, fp32 -> bf16 conversion
// ---------------------------------------------------------------------------
__global__ __launch_bounds__(256) void prep_kernel(
    const float* __restrict__ z, __bf16* __restrict__ zh,
    float* __restrict__ norms, float* __restrict__ coef) {
  int row = blockIdx.x;
  int t = threadIdx.x;                 // 0..255, one thread per column
  float x = z[(size_t)row * kD + t];
  zh[(size_t)row * kD + t] = (__bf16)x;
  float sq = x * x;
  for (int off = 32; off > 0; off >>= 1) sq += __shfl_down(sq, off, 64);
  __shared__ float part[4];
  int lane = t & 63, w = t >> 6;
  if (lane == 0) part[w] = sq;
  __syncthreads();
  if (t == 0) {
    float ns = part[0] + part[1] + part[2] + part[3];
    norms[row] = ns;
    coef[row] = -(kNU + (float)kD) / (kNU + ns);   // sigma=1
  }
}

// ---------------------------------------------------------------------------
// K2: fused gram-tile GEMM (bf16 MFMA) + dist_sq histogram (4096 bins, w=0.25)
// Block = 256 threads = 4 waves (2x2), block tile 128x128, wave tile 64x64.
// ---------------------------------------------------------------------------
__global__ __launch_bounds__(256) void gemm_hist(
    const __bf16* __restrict__ zh, const float* __restrict__ norms,
    unsigned int* __restrict__ ghist) {
  __shared__ unsigned int hist[4096];
  __shared__ float nR[128], nC[128];
  int tid = threadIdx.x;
  for (int i = tid; i < 4096; i += 256) hist[i] = 0;

  int bRow = blockIdx.y * 128, bCol = blockIdx.x * 128;
  if (tid < 128) nR[tid] = norms[bRow + tid];
  else           nC[tid - 128] = norms[bCol + tid - 128];

  int lane = tid & 63;
  int w = tid >> 6;
  int waveM = (w >> 1) * 64, waveN = (w & 1) * 64;
  int quad = lane >> 4, l15 = lane & 15;

  f32x4 acc[4][4] = {};
  const __bf16* aBase = zh + (size_t)(bRow + waveM + l15) * kD + quad * 8;
  const __bf16* bBase = zh + (size_t)(bCol + waveN + l15) * kD + quad * 8;

  for (int kk = 0; kk < kD; kk += 32) {
    bf16x8 aF[4], bF[4];
#pragma unroll
    for (int mi = 0; mi < 4; mi++)
      aF[mi] = *(const bf16x8*)(aBase + (size_t)mi * 16 * kD + kk);
#pragma unroll
    for (int ni = 0; ni < 4; ni++)
      bF[ni] = *(const bf16x8*)(bBase + (size_t)ni * 16 * kD + kk);
#pragma unroll
    for (int mi = 0; mi < 4; mi++)
#pragma unroll
      for (int ni = 0; ni < 4; ni++)
        acc[mi][ni] = __builtin_amdgcn_mfma_f32_16x16x32_bf16(
            aF[mi], bF[ni], acc[mi][ni], 0, 0, 0);
  }
  __syncthreads();  // hist zeroed + norms staged visible

#pragma unroll
  for (int mi = 0; mi < 4; mi++) {
    int rl0 = waveM + mi * 16 + quad * 4;
#pragma unroll
    for (int r = 0; r < 4; r++) {
      float ni_ = nR[rl0 + r];
#pragma unroll
      for (int nj = 0; nj < 4; nj++) {
        int cl = waveN + nj * 16 + l15;
        float g = acc[mi][nj][r];
        float dist = fmaxf(ni_ + nC[cl] - 2.0f * g, 0.0f);
        int bin = (int)(dist * 4.0f);
        bin = bin > 4095 ? 4095 : bin;
        atomicAdd(&hist[bin], 1u);
      }
    }
  }
  __syncthreads();
  for (int i = tid; i < 4096; i += 256) {
    unsigned int h = hist[i];
    if (h) atomicAdd(&ghist[i], h);
  }
}

// ---------------------------------------------------------------------------
// K3: find (lower) median from histogram, compute alpha
// ---------------------------------------------------------------------------
__global__ __launch_bounds__(256) void median_kernel(
    const unsigned int* __restrict__ ghist, float* __restrict__ alpha_out) {
  __shared__ unsigned int csum[256];
  int t = threadIdx.x;
  unsigned int s = 0;
  for (int u = 0; u < 16; u++) s += ghist[t * 16 + u];
  csum[t] = s;
  __syncthreads();
  if (t == 0) {
    // sorted index (n*n-1)//2 zero-based -> 8388608-th smallest (1-based)
    const unsigned long long target = ((unsigned long long)kN * kN - 1) / 2 + 1;
    unsigned long long cum = 0;
    int chunk = 255;
    for (int c = 0; c < 256; c++) {
      if (cum + csum[c] >= target) { chunk = c; break; }
      cum += csum[c];
    }
    for (int u = 0; u < 16; u++) {
      unsigned int h = ghist[chunk * 16 + u];
      if (cum + h >= target) {
        int b = chunk * 16 + u;
        float frac = (float)(target - cum) / (float)h;   // in (0,1]
        float med = ((float)b + frac) * 0.25f;
        alpha_out[0] = 1.0f / (med + 1e-6f);
        break;
      }
      cum += h;
    }
  }
}

// ---------------------------------------------------------------------------
// K4: fused gram-tile GEMM + k_stein accumulation (skip diagonal)
// ---------------------------------------------------------------------------
__global__ __launch_bounds__(256) void gemm_loss(
    const __bf16* __restrict__ zh, const float* __restrict__ norms,
    const float* __restrict__ coef, const float* __restrict__ alpha_p,
    double* __restrict__ acc_out) {
  __shared__ float nR[128], nC[128], cR[128], cC[128];
  __shared__ double dpart[4];
  int tid = threadIdx.x;
  int bRow = blockIdx.y * 128, bCol = blockIdx.x * 128;
  if (tid < 128) { nR[tid] = norms[bRow + tid]; cR[tid] = coef[bRow + tid]; }
  else { int u = tid - 128; nC[u] = norms[bCol + u]; cC[u] = coef[bCol + u]; }

  int lane = tid & 63;
  int w = tid >> 6;
  int waveM = (w >> 1) * 64, waveN = (w & 1) * 64;
  int quad = lane >> 4, l15 = lane & 15;

  f32x4 acc[4][4] = {};
  const __bf16* aBase = zh + (size_t)(bRow + waveM + l15) * kD + quad * 8;
  const __bf16* bBase = zh + (size_t)(bCol + waveN + l15) * kD + quad * 8;

  for (int kk = 0; kk < kD; kk += 32) {
    bf16x8 aF[4], bF[4];
#pragma unroll
    for (int mi = 0; mi < 4; mi++)
      aF[mi] = *(const bf16x8*)(aBase + (size_t)mi * 16 * kD + kk);
#pragma unroll
    for (int ni = 0; ni < 4; ni++)
      bF[ni] = *(const bf16x8*)(bBase + (size_t)ni * 16 * kD + kk);
#pragma unroll
    for (int mi = 0; mi < 4; mi++)
#pragma unroll
      for (int ni = 0; ni < 4; ni++)
        acc[mi][ni] = __builtin_amdgcn_mfma_f32_16x16x32_bf16(
            aF[mi], bF[ni], acc[mi][ni], 0, 0, 0);
  }
  __syncthreads();

  const float alpha = alpha_p[0];
  float part = 0.0f;
#pragma unroll
  for (int mi = 0; mi < 4; mi++) {
    int rl0 = waveM + mi * 16 + quad * 4;
#pragma unroll
    for (int r = 0; r < 4; r++) {
      int rl = rl0 + r;
      float ni_ = nR[rl];
      float ci  = cR[rl];
      int rg = bRow + rl;
#pragma unroll
      for (int nj = 0; nj < 4; nj++) {
        int cl = waveN + nj * 16 + l15;
        int cg = bCol + cl;
        float g = acc[mi][nj][r];
        float njv = nC[cl];
        float cj  = cC[cl];
        float dist = fmaxf(ni_ + njv - 2.0f * g, 0.0f);
        float base = fmaf(alpha, dist, 1.0f);
        float rq  = rsqrtf(base);      // base^-0.5 = K
        float rq2 = rq * rq;           // 1/base
        float gc  = -alpha * rq * rq2; // grad_coeff = -2*a*beta*base^-1.5
        float ta  = ci * cj * g * rq;
        float tb  = -gc * ci * (ni_ - g);
        float tc  =  gc * cj * (g - njv);
        float lap =  gc * ((float)kD - 3.0f * alpha * dist * rq2);
        float v = ta + tb + tc + lap;
        if (rg != cg) part += v;
      }
    }
  }

  double d = (double)part;
  for (int off = 32; off > 0; off >>= 1) d += __shfl_down(d, off, 64);
  if (lane == 0) dpart[w] = d;
  __syncthreads();
  if (tid == 0) {
    atomicAdd(acc_out, dpart[0] + dpart[1] + dpart[2] + dpart[3]);
  }
}

// ---------------------------------------------------------------------------
// K5: finalize
// ---------------------------------------------------------------------------
__global__ void finalize_kernel(const double* __restrict__ acc,
                                float* __restrict__ out) {
  out[0] = (float)(acc[0] / ((double)kN * (double)(kN - 1)));
}

// ---------------------------------------------------------------------------
extern "C" void kernel_launch(void* const* d_in, const int* in_sizes, int n_in,
                              void* d_out, int out_size, void* d_ws, size_t ws_size,
                              hipStream_t stream) {
  const float* z = (const float*)d_in[0];
  float* out = (float*)d_out;

  char* ws = (char*)d_ws;
  __bf16* zh = (__bf16*)ws;                                   // 2 MB
  float* norms = (float*)(ws + (size_t)kN * kD * 2);          // 16 KB
  float* coef  = norms + kN;                                  // 16 KB
  unsigned int* ghist = (unsigned int*)(coef + kN);           // 16 KB
  float* alpha = (float*)(ghist + 4096);                      // 4 B (+4 pad)
  double* accd = (double*)(alpha + 2);                        // 8 B, 8-aligned

  // zero: histogram + alpha + accumulator (re-poisoned to 0xAA each call)
  hipMemsetAsync(ghist, 0, 4096 * sizeof(unsigned int) + 16, stream);

  prep_kernel<<<kN, 256, 0, stream>>>(z, zh, norms, coef);

  dim3 grid(kN / 128, kN / 128);
  gemm_hist<<<grid, 256, 0, stream>>>(zh, norms, ghist);
  median_kernel<<<1, 256, 0, stream>>>(ghist, alpha);
  gemm_loss<<<grid, 256, 0, stream>>>(zh, norms, coef, alpha, accd);
  finalize_kernel<<<1, 1, 0, stream>>>(accd, out);
}

// Round 2
// 103.475 us; speedup vs baseline: 1.4833x; 1.4833x over previous
//
#include <hip/hip_runtime.h>
#include <hip/hip_bf16.h>

// Problem constants
constexpr int   kN  = 4096;
constexpr int   kD  = 256;
constexpr float kNU = 3.0f;
constexpr int   kNB = kN / 128;               // 32 block-rows/cols
constexpr int   kNPairs = kNB * (kNB + 1) / 2; // 528 upper-tri block pairs

using bf16x8 = __attribute__((ext_vector_type(8))) __bf16;
using bf16x4 = __attribute__((ext_vector_type(4))) __bf16;
using f32x4  = __attribute__((ext_vector_type(4))) float;

// ---------------------------------------------------------------------------
// K1: per-row norms + coeff + fp32->bf16; also zero ghist/accd (no memset)
// One wave per row, float4 loads. grid = 1024 blocks x 256 threads.
// ---------------------------------------------------------------------------
__global__ __launch_bounds__(256) void prep_kernel(
    const float* __restrict__ z, __bf16* __restrict__ zh,
    float* __restrict__ norms, float* __restrict__ coef,
    unsigned int* __restrict__ ghist, double* __restrict__ accd) {
  int tid = threadIdx.x;
  if (blockIdx.x < 16) ghist[blockIdx.x * 256 + tid] = 0u;
  if (blockIdx.x == 16 && tid == 0) accd[0] = 0.0;

  int w = tid >> 6, lane = tid & 63;
  int row = blockIdx.x * 4 + w;
  const float4 v = *(const float4*)(z + (size_t)row * kD + lane * 4);
  bf16x4 h;
  h[0] = (__bf16)v.x; h[1] = (__bf16)v.y; h[2] = (__bf16)v.z; h[3] = (__bf16)v.w;
  *(bf16x4*)(zh + (size_t)row * kD + lane * 4) = h;

  float sq = v.x * v.x + v.y * v.y + v.z * v.z + v.w * v.w;
  for (int off = 32; off > 0; off >>= 1) sq += __shfl_down(sq, off, 64);
  if (lane == 0) {
    norms[row] = sq;
    coef[row] = -(kNU + (float)kD) / (kNU + sq);   // sigma = 1
  }
}

// ---------------------------------------------------------------------------
// Shared gram-tile main loop: 128x128 tile, BK=64, global_load_lds staging,
// XOR-swizzled 16B chunks for conflict-free ds_read_b128.
// LDS layout: slot s (16B) holds row = s>>3, stored-chunk cp = s&7,
// logical chunk c = cp ^ (row&7).
// ---------------------------------------------------------------------------
__device__ __forceinline__ void gram_tile(
    const __bf16* __restrict__ zh, int bRow, int bCol, int tid,
    __bf16* ldsA, __bf16* ldsB, f32x4 acc[4][4]) {
  int lane = tid & 63, w = tid >> 6;
  int quad = lane >> 4, l15 = lane & 15;
  int waveM = (w >> 1) * 64, waveN = (w & 1) * 64;

  for (int kc = 0; kc < 4; kc++) {
    if (kc) __syncthreads();           // prior chunk's reads done
#pragma unroll
    for (int s = 0; s < 4; s++) {
      int slot = (w * 4 + s) * 64 + lane;      // 0..1023
      int row = slot >> 3;
      int cp = slot & 7;
      int c = cp ^ (row & 7);                  // logical chunk this slot holds
      const __bf16* gA = zh + (size_t)(bRow + row) * kD + kc * 64 + c * 8;
      const __bf16* gB = zh + (size_t)(bCol + row) * kD + kc * 64 + c * 8;
      __builtin_amdgcn_global_load_lds(
          (const __attribute__((address_space(1))) void*)gA,
          (__attribute__((address_space(3))) void*)(ldsA + (size_t)(w * 4 + s) * 512),
          16, 0, 0);
      __builtin_amdgcn_global_load_lds(
          (const __attribute__((address_space(1))) void*)gB,
          (__attribute__((address_space(3))) void*)(ldsB + (size_t)(w * 4 + s) * 512),
          16, 0, 0);
    }
    __syncthreads();                   // staging visible
#pragma unroll
    for (int ks = 0; ks < 2; ks++) {
      bf16x8 aF[4], bF[4];
#pragma unroll
      for (int mi = 0; mi < 4; mi++) {
        int row = waveM + mi * 16 + l15;
        int cp = ((ks << 2) | quad) ^ (row & 7);
        aF[mi] = *(const bf16x8*)(ldsA + row * 64 + cp * 8);
      }
#pragma unroll
      for (int ni = 0; ni < 4; ni++) {
        int row = waveN + ni * 16 + l15;
        int cp = ((ks << 2) | quad) ^ (row & 7);
        bF[ni] = *(const bf16x8*)(ldsB + row * 64 + cp * 8);
      }
#pragma unroll
      for (int mi = 0; mi < 4; mi++)
#pragma unroll
        for (int ni = 0; ni < 4; ni++)
          acc[mi][ni] = __builtin_amdgcn_mfma_f32_16x16x32_bf16(
              aF[mi], bF[ni], acc[mi][ni], 0, 0, 0);
    }
  }
}

__device__ __forceinline__ void tri_decode(int b, int& by, int& bx) {
  int t = b; by = 0;
  while (t >= kNB - by) { t -= kNB - by; by++; }
  bx = by + t;
}

// ---------------------------------------------------------------------------
// K2: gram + dist_sq histogram (4096 bins, width 0.25), upper-tri blocks only
// ---------------------------------------------------------------------------
__global__ __launch_bounds__(256) void gemm_hist(
    const __bf16* __restrict__ zh, const float* __restrict__ norms,
    unsigned int* __restrict__ ghist) {
  __shared__ __bf16 ldsA[128 * 64], ldsB[128 * 64];
  __shared__ unsigned int hist[4096];
  __shared__ float nR[128], nC[128];
  int tid = threadIdx.x;
  for (int i = tid; i < 4096; i += 256) hist[i] = 0;

  int by, bx; tri_decode(blockIdx.x, by, bx);
  int bRow = by * 128, bCol = bx * 128;
  if (tid < 128) nR[tid] = norms[bRow + tid];
  else           nC[tid - 128] = norms[bCol + tid - 128];

  int lane = tid & 63, w = tid >> 6;
  int quad = lane >> 4, l15 = lane & 15;
  int waveM = (w >> 1) * 64, waveN = (w & 1) * 64;

  f32x4 acc[4][4] = {};
  gram_tile(zh, bRow, bCol, tid, ldsA, ldsB, acc);

  unsigned int wgt = (by == bx) ? 1u : 2u;
#pragma unroll
  for (int mi = 0; mi < 4; mi++) {
    int rl0 = waveM + mi * 16 + quad * 4;
#pragma unroll
    for (int r = 0; r < 4; r++) {
      float ni_ = nR[rl0 + r];
#pragma unroll
      for (int nj = 0; nj < 4; nj++) {
        int cl = waveN + nj * 16 + l15;
        float g = acc[mi][nj][r];
        float dist = fmaxf(ni_ + nC[cl] - 2.0f * g, 0.0f);
        int bin = (int)(dist * 4.0f);
        bin = bin > 4095 ? 4095 : bin;
        atomicAdd(&hist[bin], wgt);
      }
    }
  }
  __syncthreads();
  for (int i = tid; i < 4096; i += 256) {
    unsigned int h = hist[i];
    if (h) atomicAdd(&ghist[i], h);
  }
}

// ---------------------------------------------------------------------------
// K3: median (lower-middle element) from histogram -> alpha
// ---------------------------------------------------------------------------
__global__ __launch_bounds__(256) void median_kernel(
    const unsigned int* __restrict__ ghist, float* __restrict__ alpha_out) {
  __shared__ unsigned int csum[256];
  int t = threadIdx.x;
  unsigned int s = 0;
  for (int u = 0; u < 16; u++) s += ghist[t * 16 + u];
  csum[t] = s;
  __syncthreads();
  if (t == 0) {
    const unsigned long long target = ((unsigned long long)kN * kN - 1) / 2 + 1;
    unsigned long long cum = 0;
    int chunk = 255;
    for (int c = 0; c < 256; c++) {
      if (cum + csum[c] >= target) { chunk = c; break; }
      cum += csum[c];
    }
    for (int u = 0; u < 16; u++) {
      unsigned int h = ghist[chunk * 16 + u];
      if (cum + h >= target) {
        int b = chunk * 16 + u;
        float frac = (float)(target - cum) / (float)h;
        float med = ((float)b + frac) * 0.25f;
        alpha_out[0] = 1.0f / (med + 1e-6f);
        break;
      }
      cum += h;
    }
  }
}

// ---------------------------------------------------------------------------
// K4: gram + k_stein accumulation, upper-tri blocks, pair-symmetry weight 2
// ---------------------------------------------------------------------------
__global__ __launch_bounds__(256) void gemm_loss(
    const __bf16* __restrict__ zh, const float* __restrict__ norms,
    const float* __restrict__ coef, const float* __restrict__ alpha_p,
    double* __restrict__ acc_out) {
  __shared__ __bf16 ldsA[128 * 64], ldsB[128 * 64];
  __shared__ float nR[128], nC[128], cR[128], cC[128];
  __shared__ double dpart[4];
  int tid = threadIdx.x;

  int by, bx; tri_decode(blockIdx.x, by, bx);
  int bRow = by * 128, bCol = bx * 128;
  if (tid < 128) { nR[tid] = norms[bRow + tid]; cR[tid] = coef[bRow + tid]; }
  else { int u = tid - 128; nC[u] = norms[bCol + u]; cC[u] = coef[bCol + u]; }

  int lane = tid & 63, w = tid >> 6;
  int quad = lane >> 4, l15 = lane & 15;
  int waveM = (w >> 1) * 64, waveN = (w & 1) * 64;

  f32x4 acc[4][4] = {};
  gram_tile(zh, bRow, bCol, tid, ldsA, ldsB, acc);

  const float alpha = alpha_p[0];
  const float wf = (by == bx) ? 1.0f : 2.0f;
  float part = 0.0f;
#pragma unroll
  for (int mi = 0; mi < 4; mi++) {
    int rl0 = waveM + mi * 16 + quad * 4;
#pragma unroll
    for (int r = 0; r < 4; r++) {
      int rl = rl0 + r;
      float ni_ = nR[rl];
      float ci  = cR[rl];
      int rg = bRow + rl;
#pragma unroll
      for (int nj = 0; nj < 4; nj++) {
        int cl = waveN + nj * 16 + l15;
        int cg = bCol + cl;
        float g = acc[mi][nj][r];
        float njv = nC[cl];
        float cj  = cC[cl];
        float dist = fmaxf(ni_ + njv - 2.0f * g, 0.0f);
        float base = fmaf(alpha, dist, 1.0f);
        float rq  = rsqrtf(base);      // K = base^-0.5
        float rq2 = rq * rq;           // 1/base
        float gc  = -alpha * rq * rq2; // grad_coeff
        float ta  = ci * cj * g * rq;
        float tb  = -gc * ci * (ni_ - g);
        float tc  =  gc * cj * (g - njv);
        float lap =  gc * ((float)kD - 3.0f * alpha * dist * rq2);
        float v = ta + tb + tc + lap;
        if (rg != cg) part += wf * v;
      }
    }
  }

  double d = (double)part;
  for (int off = 32; off > 0; off >>= 1) d += __shfl_down(d, off, 64);
  if (lane == 0) dpart[w] = d;
  __syncthreads();
  if (tid == 0) atomicAdd(acc_out, dpart[0] + dpart[1] + dpart[2] + dpart[3]);
}

// ---------------------------------------------------------------------------
// K5: finalize
// ---------------------------------------------------------------------------
__global__ void finalize_kernel(const double* __restrict__ acc,
                                float* __restrict__ out) {
  out[0] = (float)(acc[0] / ((double)kN * (double)(kN - 1)));
}

// ---------------------------------------------------------------------------
extern "C" void kernel_launch(void* const* d_in, const int* in_sizes, int n_in,
                              void* d_out, int out_size, void* d_ws, size_t ws_size,
                              hipStream_t stream) {
  const float* z = (const float*)d_in[0];
  float* out = (float*)d_out;

  char* ws = (char*)d_ws;
  __bf16* zh = (__bf16*)ws;                                   // 2 MB
  float* norms = (float*)(ws + (size_t)kN * kD * 2);
  float* coef  = norms + kN;
  unsigned int* ghist = (unsigned int*)(coef + kN);
  float* alpha = (float*)(ghist + 4096);
  double* accd = (double*)(alpha + 2);                        // 8-aligned

  prep_kernel<<<kN / 4, 256, 0, stream>>>(z, zh, norms, coef, ghist, accd);
  gemm_hist<<<kNPairs, 256, 0, stream>>>(zh, norms, ghist);
  median_kernel<<<1, 256, 0, stream>>>(ghist, alpha);
  gemm_loss<<<kNPairs, 256, 0, stream>>>(zh, norms, coef, alpha, accd);
  finalize_kernel<<<1, 1, 0, stream>>>(accd, out);
}

// Round 3
// 101.787 us; speedup vs baseline: 1.5079x; 1.0166x over previous
//
#include <hip/hip_runtime.h>
#include <hip/hip_bf16.h>

// Problem constants
constexpr int   kN  = 4096;
constexpr int   kD  = 256;
constexpr float kNU = 3.0f;
constexpr int   kNB = kN / 128;                // 32 block-rows/cols
constexpr int   kNPairs = kNB * (kNB + 1) / 2; // 528 upper-tri block pairs

using bf16x8 = __attribute__((ext_vector_type(8))) __bf16;
using bf16x4 = __attribute__((ext_vector_type(4))) __bf16;
using f32x4  = __attribute__((ext_vector_type(4))) float;

// ---------------------------------------------------------------------------
// K1: per-row norms + coeff + fp32->bf16; also zero ghist/accd (no memset)
// ---------------------------------------------------------------------------
__global__ __launch_bounds__(256) void prep_kernel(
    const float* __restrict__ z, __bf16* __restrict__ zh,
    float* __restrict__ norms, float* __restrict__ coef,
    unsigned int* __restrict__ ghist, double* __restrict__ accd) {
  int tid = threadIdx.x;
  if (blockIdx.x < 16) ghist[blockIdx.x * 256 + tid] = 0u;
  if (blockIdx.x == 16 && tid == 0) accd[0] = 0.0;

  int w = tid >> 6, lane = tid & 63;
  int row = blockIdx.x * 4 + w;
  const float4 v = *(const float4*)(z + (size_t)row * kD + lane * 4);
  bf16x4 h;
  h[0] = (__bf16)v.x; h[1] = (__bf16)v.y; h[2] = (__bf16)v.z; h[3] = (__bf16)v.w;
  *(bf16x4*)(zh + (size_t)row * kD + lane * 4) = h;

  float sq = v.x * v.x + v.y * v.y + v.z * v.z + v.w * v.w;
  for (int off = 32; off > 0; off >>= 1) sq += __shfl_down(sq, off, 64);
  if (lane == 0) {
    norms[row] = sq;
    coef[row] = -(kNU + (float)kD) / (kNU + sq);   // sigma = 1
  }
}

// ---------------------------------------------------------------------------
// Gram tile main loop (128x128, BK=64, global_load_lds, XOR-swizzled chunks)
// ---------------------------------------------------------------------------
__device__ __forceinline__ void gram_tile(
    const __bf16* __restrict__ zh, int bRow, int bCol, int tid,
    __bf16* ldsA, __bf16* ldsB, f32x4 acc[4][4]) {
  int lane = tid & 63, w = tid >> 6;
  int quad = lane >> 4, l15 = lane & 15;
  int waveM = (w >> 1) * 64, waveN = (w & 1) * 64;

  for (int kc = 0; kc < 4; kc++) {
    if (kc) __syncthreads();
#pragma unroll
    for (int s = 0; s < 4; s++) {
      int slot = (w * 4 + s) * 64 + lane;
      int row = slot >> 3;
      int cp = slot & 7;
      int c = cp ^ (row & 7);
      const __bf16* gA = zh + (size_t)(bRow + row) * kD + kc * 64 + c * 8;
      const __bf16* gB = zh + (size_t)(bCol + row) * kD + kc * 64 + c * 8;
      __builtin_amdgcn_global_load_lds(
          (const __attribute__((address_space(1))) void*)gA,
          (__attribute__((address_space(3))) void*)(ldsA + (size_t)(w * 4 + s) * 512),
          16, 0, 0);
      __builtin_amdgcn_global_load_lds(
          (const __attribute__((address_space(1))) void*)gB,
          (__attribute__((address_space(3))) void*)(ldsB + (size_t)(w * 4 + s) * 512),
          16, 0, 0);
    }
    __syncthreads();
#pragma unroll
    for (int ks = 0; ks < 2; ks++) {
      bf16x8 aF[4], bF[4];
#pragma unroll
      for (int mi = 0; mi < 4; mi++) {
        int row = waveM + mi * 16 + l15;
        int cp = ((ks << 2) | quad) ^ (row & 7);
        aF[mi] = *(const bf16x8*)(ldsA + row * 64 + cp * 8);
      }
#pragma unroll
      for (int ni = 0; ni < 4; ni++) {
        int row = waveN + ni * 16 + l15;
        int cp = ((ks << 2) | quad) ^ (row & 7);
        bF[ni] = *(const bf16x8*)(ldsB + row * 64 + cp * 8);
      }
#pragma unroll
      for (int mi = 0; mi < 4; mi++)
#pragma unroll
        for (int ni = 0; ni < 4; ni++)
          acc[mi][ni] = __builtin_amdgcn_mfma_f32_16x16x32_bf16(
              aF[mi], bF[ni], acc[mi][ni], 0, 0, 0);
    }
  }
}

__device__ __forceinline__ void tri_decode(int b, int& by, int& bx) {
  int t = b; by = 0;
  while (t >= kNB - by) { t -= kNB - by; by++; }
  bx = by + t;
}

// ---------------------------------------------------------------------------
// K2: gram -> dist_sq; store dist tile to ws + histogram (4096 bins, w=0.25)
// ---------------------------------------------------------------------------
__global__ __launch_bounds__(256) void gemm_hist(
    const __bf16* __restrict__ zh, const float* __restrict__ norms,
    unsigned int* __restrict__ ghist, float* __restrict__ dist_out) {
  __shared__ __bf16 ldsA[128 * 64], ldsB[128 * 64];
  __shared__ unsigned int hist[4096];
  __shared__ float nR[128], nC[128];
  int tid = threadIdx.x;
  for (int i = tid; i < 4096; i += 256) hist[i] = 0;

  int by, bx; tri_decode(blockIdx.x, by, bx);
  int bRow = by * 128, bCol = bx * 128;
  if (tid < 128) nR[tid] = norms[bRow + tid];
  else           nC[tid - 128] = norms[bCol + tid - 128];

  int lane = tid & 63, w = tid >> 6;
  int quad = lane >> 4, l15 = lane & 15;
  int waveM = (w >> 1) * 64, waveN = (w & 1) * 64;

  f32x4 acc[4][4] = {};
  gram_tile(zh, bRow, bCol, tid, ldsA, ldsB, acc);

  float* dtile = dist_out + (size_t)blockIdx.x * 16384;
  unsigned int wgt = (by == bx) ? 1u : 2u;
#pragma unroll
  for (int mi = 0; mi < 4; mi++) {
    int rl0 = waveM + mi * 16 + quad * 4;
#pragma unroll
    for (int r = 0; r < 4; r++) {
      int rl = rl0 + r;
      float ni_ = nR[rl];
#pragma unroll
      for (int nj = 0; nj < 4; nj++) {
        int cl = waveN + nj * 16 + l15;
        float g = acc[mi][nj][r];
        float dist = fmaxf(ni_ + nC[cl] - 2.0f * g, 0.0f);
        dtile[rl * 128 + cl] = dist;
        int bin = (int)(dist * 4.0f);
        bin = bin > 4095 ? 4095 : bin;
        atomicAdd(&hist[bin], wgt);
      }
    }
  }
  __syncthreads();
  for (int i = tid; i < 4096; i += 256) {
    unsigned int h = hist[i];
    if (h) atomicAdd(&ghist[i], h);
  }
}

// ---------------------------------------------------------------------------
// K3: parallel median (lower-middle element) -> alpha
// ---------------------------------------------------------------------------
__global__ __launch_bounds__(256) void median_kernel(
    const unsigned int* __restrict__ ghist, float* __restrict__ alpha_out) {
  __shared__ unsigned long long scan[256];
  int t = threadIdx.x;
  unsigned int own = 0;
#pragma unroll
  for (int u = 0; u < 16; u++) own += ghist[t * 16 + u];
  scan[t] = own;
  __syncthreads();
  // Hillis-Steele inclusive scan
#pragma unroll
  for (int off = 1; off < 256; off <<= 1) {
    unsigned long long v = (t >= off) ? scan[t - off] : 0ull;
    __syncthreads();
    scan[t] += v;
    __syncthreads();
  }
  const unsigned long long target = ((unsigned long long)kN * kN - 1) / 2 + 1;
  unsigned long long incl = scan[t];
  unsigned long long excl = incl - own;
  if (incl >= target && excl < target) {   // exactly one thread
    unsigned long long cum = excl;
#pragma unroll
    for (int u = 0; u < 16; u++) {
      unsigned int h = ghist[t * 16 + u];
      if (cum + h >= target) {
        int b = t * 16 + u;
        float frac = (float)(target - cum) / (float)h;
        float med = ((float)b + frac) * 0.25f;
        alpha_out[0] = 1.0f / (med + 1e-6f);
        break;
      }
      cum += h;
    }
  }
}

// ---------------------------------------------------------------------------
// K4: elementwise k_stein from stored dist tiles, weighted tri sum
// ---------------------------------------------------------------------------
__global__ __launch_bounds__(256) void loss_elem(
    const float* __restrict__ dist_in, const float* __restrict__ norms,
    const float* __restrict__ coef, const float* __restrict__ alpha_p,
    double* __restrict__ acc_out) {
  __shared__ float nR[128], nC[128], cR[128], cC[128];
  __shared__ double dpart[4];
  int tid = threadIdx.x;
  int by, bx; tri_decode(blockIdx.x, by, bx);
  int bRow = by * 128, bCol = bx * 128;
  if (tid < 128) { nR[tid] = norms[bRow + tid]; cR[tid] = coef[bRow + tid]; }
  else { int u = tid - 128; nC[u] = norms[bCol + u]; cC[u] = coef[bCol + u]; }
  __syncthreads();

  const float alpha = alpha_p[0];
  const bool diag = (by == bx);
  const float wf = diag ? 1.0f : 2.0f;
  const float4* base4 = (const float4*)(dist_in + (size_t)blockIdx.x * 16384);

  float part = 0.0f;
#pragma unroll
  for (int i = 0; i < 16; i++) {
    int o4 = tid + i * 256;          // float4 index in tile
    int row = o4 >> 5;               // (o4*4)/128
    int col0 = (o4 & 31) * 4;
    float4 dv = base4[o4];
    float ni_ = nR[row], ci = cR[row];
#pragma unroll
    for (int e = 0; e < 4; e++) {
      int col = col0 + e;
      float dist = (e == 0) ? dv.x : (e == 1) ? dv.y : (e == 2) ? dv.z : dv.w;
      float njv = nC[col], cj = cC[col];
      float g = 0.5f * (ni_ + njv - dist);
      float base = fmaf(alpha, dist, 1.0f);
      float rq  = rsqrtf(base);      // K = base^-0.5
      float rq2 = rq * rq;
      float gc  = -alpha * rq * rq2; // grad_coeff
      float ta  = ci * cj * g * rq;
      float tb  = -gc * ci * (ni_ - g);
      float tc  =  gc * cj * (g - njv);
      float lap =  gc * ((float)kD - 3.0f * alpha * dist * rq2);
      float v = ta + tb + tc + lap;
      if (!(diag && row == col)) part += wf * v;
    }
  }

  int lane = tid & 63, w = tid >> 6;
  double d = (double)part;
  for (int off = 32; off > 0; off >>= 1) d += __shfl_down(d, off, 64);
  if (lane == 0) dpart[w] = d;
  __syncthreads();
  if (tid == 0) atomicAdd(acc_out, dpart[0] + dpart[1] + dpart[2] + dpart[3]);
}

// ---------------------------------------------------------------------------
// K5: finalize
// ---------------------------------------------------------------------------
__global__ void finalize_kernel(const double* __restrict__ acc,
                                float* __restrict__ out) {
  out[0] = (float)(acc[0] / ((double)kN * (double)(kN - 1)));
}

// ---------------------------------------------------------------------------
extern "C" void kernel_launch(void* const* d_in, const int* in_sizes, int n_in,
                              void* d_out, int out_size, void* d_ws, size_t ws_size,
                              hipStream_t stream) {
  const float* z = (const float*)d_in[0];
  float* out = (float*)d_out;

  char* ws = (char*)d_ws;
  __bf16* zh = (__bf16*)ws;                                   // 2 MB
  float* norms = (float*)(ws + (size_t)kN * kD * 2);
  float* coef  = norms + kN;
  unsigned int* ghist = (unsigned int*)(coef + kN);
  float* alpha = (float*)(ghist + 4096);
  double* accd = (double*)(alpha + 2);                        // 8-aligned
  float* dist  = (float*)(ws + (4 << 20));                    // 34.6 MB @ +4MB

  prep_kernel<<<kN / 4, 256, 0, stream>>>(z, zh, norms, coef, ghist, accd);
  gemm_hist<<<kNPairs, 256, 0, stream>>>(zh, norms, ghist, dist);
  median_kernel<<<1, 256, 0, stream>>>(ghist, alpha);
  loss_elem<<<kNPairs, 256, 0, stream>>>(dist, norms, coef, alpha, accd);
  finalize_kernel<<<1, 1, 0, stream>>>(accd, out);
}